// Round 7
// baseline (385.720 us; speedup 1.0000x reference)
//
#include <hip/hip_runtime.h>

typedef unsigned short u16;
typedef short bfrag __attribute__((ext_vector_type(8)));   // 8 bf16 (4 VGPRs) for MFMA A/B
typedef float facc  __attribute__((ext_vector_type(4)));   // 4 fp32 accumulator

__device__ __forceinline__ float bf2f(u16 u) {
    union { unsigned int i; float f; } v; v.i = ((unsigned int)u) << 16; return v.f;
}
__device__ __forceinline__ u16 f2bf(float f) {
    union { float f; unsigned int i; } v; v.f = f;
    unsigned int r = v.i + 0x7FFFu + ((v.i >> 16) & 1u);
    return (u16)(r >> 16);
}

__device__ __forceinline__ void store_out(u16* p, float v)   { *p = f2bf(v); }
__device__ __forceinline__ void store_out(float* p, float v) { *p = v; }

// async global->LDS, 16B per lane; LDS dest = wave-uniform base + lane*16
__device__ __forceinline__ void gl2lds16(const u16* g, char* l) {
    __builtin_amdgcn_global_load_lds(
        (const __attribute__((address_space(1))) unsigned int*)g,
        (__attribute__((address_space(3))) unsigned int*)l,
        16, 0, 0);
}

// ---------------------------------------------------------------------------
// fp32 -> bf16 convert for the 4 weight tensors in one launch
// ---------------------------------------------------------------------------
__global__ void cvt4_k(const float* __restrict__ s0, u16* __restrict__ d0,
                       const float* __restrict__ s1, u16* __restrict__ d1,
                       const float* __restrict__ s2, u16* __restrict__ d2,
                       const float* __restrict__ s3, u16* __restrict__ d3) {
    int i = blockIdx.x * blockDim.x + threadIdx.x;
    if (i < 262144)        d0[i] = f2bf(s0[i]);
    else if (i < 1310720)  d1[i - 262144] = f2bf(s1[i - 262144]);
    else if (i < 2359296)  d2[i - 1310720] = f2bf(s2[i - 1310720]);
    else                   d3[i - 2359296] = f2bf(s3[i - 2359296]);
}

// ---------------------------------------------------------------------------
// Input transpose + fp32->bf16: xa/xb (b,256,4096) -> XT (16b, 4096, 256)
// ---------------------------------------------------------------------------
__global__ void transpose_in_k(const float* __restrict__ srcA,
                               const float* __restrict__ srcB,
                               u16* __restrict__ dst) {
    __shared__ u16 tile[64][65];
    const long SX = 1048576;  // 256*4096
    const int z  = blockIdx.z;
    const int c0 = blockIdx.x * 64;   // spatial
    const int r0 = blockIdx.y * 64;   // channel
    const int x  = threadIdx.x;
    const int y0 = threadIdx.y;
    const float* s = (z < 8 ? srcA : srcB) + (size_t)(z & 7) * SX;
    for (int i = 0; i < 8; ++i) {
        int r = y0 + i * 8;
        tile[r][x] = f2bf(s[(size_t)(r0 + r) * 4096 + c0 + x]);
    }
    __syncthreads();
    u16* d = dst + (size_t)z * SX;
    for (int i = 0; i < 8; ++i) {
        int c = y0 + i * 8;
        d[(size_t)(c0 + c) * 256 + r0 + x] = tile[x][c];
    }
}

// ---------------------------------------------------------------------------
// 128x128 NT GEMM (m97-class structure), kept for MODE 1 (conv2, small grid).
// ---------------------------------------------------------------------------
template <typename OutT, int MODE, bool PAIRED>
__global__ __launch_bounds__(256)
void gemm_nt(const u16* __restrict__ A0, const u16* __restrict__ A1, long strideA,
             const u16* __restrict__ B0, const u16* __restrict__ B1, long strideBT,
             OutT* __restrict__ C, long strideC, u16* __restrict__ CT,
             const float* __restrict__ bias, int M, int N, int K) {
    __shared__ __align__(16) char smem[32768];
    char* As = smem;
    char* Bs = smem + 16384;

    const int gx = gridDim.x, gy = gridDim.y;
    long id = blockIdx.x + (long)gx * (blockIdx.y + (long)gy * blockIdx.z);
    long total = (long)gx * gy * gridDim.z;
    long nid = (id & 7) * (total >> 3) + (id >> 3);
    const int bx = (int)(nid % gx);
    long rr = nid / gx;
    const int by = (int)(rr % gy);
    const int b  = (int)(rr / gy);

    const int m0 = bx * 128;
    const int n0 = by * 128;

    const u16* Ab; const u16* Bb;
    if (PAIRED) {
        const int bl = b & 7;
        Ab = (b < 8 ? A0 : A1) + (size_t)bl * strideA;
        Bb = (b < 8 ? B0 : B1) + (size_t)bl * strideBT;
    } else {
        Ab = A0 + (size_t)b * strideA;
        Bb = B0 + (size_t)b * strideBT;
    }

    const int t    = threadIdx.x;
    const int lane = t & 63;
    const int w    = t >> 6;
    const int wm   = (w & 1) * 64;
    const int wn   = (w >> 1) * 64;
    const int q    = lane >> 4;
    const int ln   = lane & 15;

    const int s0 = w * 64 + lane;
    const int s1 = s0 + 256;
    const int r0s = s0 >> 2, c0s = (s0 & 3) * 8;
    const int r1s = s1 >> 2, c1s = (s1 & 3) * 8;

    const u16* pA0 = Ab + (size_t)(m0 + r0s) * K + c0s;
    const u16* pA1 = Ab + (size_t)(m0 + r1s) * K + c1s;
    const u16* pB0 = Bb + (size_t)(n0 + r0s) * K + c0s;
    const u16* pB1 = Bb + (size_t)(n0 + r1s) * K + c1s;

    facc acc[4][4];
    for (int i = 0; i < 4; ++i)
        for (int j = 0; j < 4; ++j)
            acc[i][j] = (facc)0.0f;

    const int nK = K >> 6;
    for (int kt = 0; kt < nK; ++kt) {
        const int k0 = kt << 6;
        gl2lds16(pA0 + k0,      As + s0 * 16);
        gl2lds16(pA1 + k0,      As + s1 * 16);
        gl2lds16(pA0 + k0 + 32, As + 8192 + s0 * 16);
        gl2lds16(pA1 + k0 + 32, As + 8192 + s1 * 16);
        gl2lds16(pB0 + k0,      Bs + s0 * 16);
        gl2lds16(pB1 + k0,      Bs + s1 * 16);
        gl2lds16(pB0 + k0 + 32, Bs + 8192 + s0 * 16);
        gl2lds16(pB1 + k0 + 32, Bs + 8192 + s1 * 16);
        __syncthreads();
        for (int j = 0; j < 2; ++j) {
            const char* Aj = As + j * 8192;
            const char* Bj = Bs + j * 8192;
            bfrag af[4], bfr[4];
            for (int mt = 0; mt < 4; ++mt)
                af[mt] = *reinterpret_cast<const bfrag*>(Aj + (wm + mt * 16 + ln) * 64 + q * 16);
            for (int nt = 0; nt < 4; ++nt)
                bfr[nt] = *reinterpret_cast<const bfrag*>(Bj + (wn + nt * 16 + ln) * 64 + q * 16);
            for (int mt = 0; mt < 4; ++mt)
                for (int nt = 0; nt < 4; ++nt)
                    acc[mt][nt] = __builtin_amdgcn_mfma_f32_16x16x32_bf16(af[mt], bfr[nt], acc[mt][nt], 0, 0, 0);
        }
        __syncthreads();
    }

    if (MODE == 0) {
        u16* Cb = (u16*)C + (size_t)b * strideC;
        u16* dump = (u16*)smem;
        for (int mt = 0; mt < 4; ++mt)
            for (int nt = 0; nt < 4; ++nt)
                for (int r = 0; r < 4; ++r)
                    dump[(wm + mt * 16 + q * 4 + r) * 128 + wn + nt * 16 + ln] = f2bf(acc[mt][nt][r]);
        __syncthreads();
        for (int i = 0; i < 8; ++i) {
            const int row = w * 32 + i * 4 + (lane >> 4);
            const uint4 v = *reinterpret_cast<const uint4*>(dump + row * 128 + (lane & 15) * 8);
            *reinterpret_cast<uint4*>(Cb + (size_t)(m0 + row) * N + n0 + (lane & 15) * 8) = v;
        }
    } else {
        OutT* Cb = C + (size_t)b * strideC;
        for (int mt = 0; mt < 4; ++mt) {
            const int rbase = m0 + wm + mt * 16 + q * 4;
            for (int nt = 0; nt < 4; ++nt) {
                const int col = n0 + wn + nt * 16 + ln;
                for (int r = 0; r < 4; ++r)
                    store_out(&Cb[(size_t)(rbase + r) * N + col], acc[mt][nt][r] + bias[rbase + r]);
            }
        }
    }
}

// ---------------------------------------------------------------------------
// 256x256 8-phase NT GEMM (T2+T3+T4+T5), bf16 in, K multiple of 128.
// 512 thr = 8 waves (2M x 4N), per-wave 128x64 C. LDS 128 KiB, dbuf.
// Swizzle: physical chunk p of row r holds logical chunk p ^ (r&7) —
// pre-swizzled per-lane GLOBAL source (gl2lds dest linear) + same XOR on
// ds_read addresses.
// MODE8: 0 = plain bf16 C store; 2 = +bias +fused 2x2 maxpool writing
//   FA (ch-major, via C) + FAT (spatial-major, via CT). MODE8=2 permutes
//   B rows at staging so tile col c = 4*(yp*32+xp) + 2*dy + dx maps to
//   spatial (4*by + 2*yp + dy)*64 + 2*xp + dx; pool window = lanes
//   4a..4a+3 of each 16-lane group -> in-register shfl_xor butterfly,
//   then LDS-transposed dual dumps -> fully coalesced uint4 stores.
//   (round-6: dumpP2 stride 72 u16 for 16B-aligned rows. round-7 fix:
//   FAT pass decode spl=linear>>5, cq=linear&31 — the >>6/&63 decode
//   skipped half the rows and wrote outside the block's column slab.)
// Stage schedule + vmcnt ledger: see round-1/2 notes (unchanged).
// ---------------------------------------------------------------------------
#define BAR8() do { asm volatile("" ::: "memory"); __builtin_amdgcn_s_barrier(); asm volatile("" ::: "memory"); } while (0)
#define VM6() asm volatile("s_waitcnt vmcnt(6)" ::: "memory")
#define VM0() asm volatile("s_waitcnt vmcnt(0)" ::: "memory")

#define LDA8(BUF, MH) \
    _Pragma("unroll") for (int mf = 0; mf < 4; ++mf) { \
        _Pragma("unroll") for (int ks = 0; ks < 2; ++ks) \
            a[mf][ks] = *reinterpret_cast<const bfrag*>(Ab8 + (BUF) * 32768 + \
                (wr * 128 + ((MH) * 4 + mf) * 16 + ln) * 128 + (((ks * 4 + q) ^ ln7) << 4)); }

#define LDB8(BUF, NH) \
    _Pragma("unroll") for (int nf = 0; nf < 2; ++nf) { \
        _Pragma("unroll") for (int ks = 0; ks < 2; ++ks) \
            bb[(NH) * 2 + nf][ks] = *reinterpret_cast<const bfrag*>(Bb8 + (BUF) * 32768 + \
                (wc * 64 + ((NH) * 2 + nf) * 16 + ln) * 128 + (((ks * 4 + q) ^ ln7) << 4)); }

#define MM8(MH, NH) \
    _Pragma("unroll") for (int mf = 0; mf < 4; ++mf) \
    _Pragma("unroll") for (int nf = 0; nf < 2; ++nf) \
    _Pragma("unroll") for (int ks = 0; ks < 2; ++ks) \
        acc[(MH) * 4 + mf][(NH) * 2 + nf] = __builtin_amdgcn_mfma_f32_16x16x32_bf16( \
            a[mf][ks], bb[(NH) * 2 + nf][ks], acc[(MH) * 4 + mf][(NH) * 2 + nf], 0, 0, 0);

#define STA8(KT, BUF, H, R) gl2lds16(pAs + (size_t)((H) * 128 + (R) * 8) * K + (KT) * 64, \
        Ab8 + (BUF) * 32768 + (H) * 16384 + (w * 2 + (R)) * 1024 + lane * 16)
#define STB8(KT, BUF, H, R) gl2lds16(pBs + (size_t)((H) * 128 + (R) * BR8) * K + (KT) * 64, \
        Bb8 + (BUF) * 32768 + (H) * 16384 + (w * 2 + (R)) * 1024 + lane * 16)

template <bool PAIRED, int MODE8>
__global__ __launch_bounds__(512, 1)
void gemm8_nt(const u16* __restrict__ A0, const u16* __restrict__ A1, long strideA,
              const u16* __restrict__ B0, const u16* __restrict__ B1, long strideBT,
              u16* __restrict__ C, long strideC, u16* __restrict__ CT,
              const float* __restrict__ bias, int N, int K) {
    constexpr bool POOL8 = (MODE8 == 2);
    constexpr int BR8 = POOL8 ? 4 : 8;   // B-stage R row-stride (pool perm)
    __shared__ __align__(16) char smem8[131072];
    char* Ab8 = smem8;
    char* Bb8 = smem8 + 65536;

    const int gx = gridDim.x, gy = gridDim.y;
    long id = blockIdx.x + (long)gx * (blockIdx.y + (long)gy * blockIdx.z);
    long total = (long)gx * gy * gridDim.z;
    long nid = (id & 7) * (total >> 3) + (id >> 3);
    const int bx = (int)(nid % gx);
    long rr = nid / gx;
    const int by = (int)(rr % gy);
    const int b  = (int)(rr / gy);
    const int m0 = bx * 256, n0 = by * 256;

    const u16* Ab; const u16* Bb;
    if (PAIRED) {
        const int bl = b & 7;
        Ab = (b < 8 ? A0 : A1) + (size_t)bl * strideA;
        Bb = (b < 8 ? B0 : B1) + (size_t)bl * strideBT;
    } else {
        Ab = A0 + (size_t)b * strideA;
        Bb = B0 + (size_t)b * strideBT;
    }

    const int t    = threadIdx.x;
    const int lane = t & 63;
    const int w    = t >> 6;          // 0..7
    const int wr   = w >> 2;          // 0..1  (M half: rows wr*128..+127)
    const int wc   = w & 3;           // 0..3  (N quarter: cols wc*64..+63)
    const int q    = lane >> 4;
    const int ln   = lane & 15;
    const int ln7  = ln & 7;
    const int l8   = lane >> 3;       // 0..7 (stage row-in-segment)
    const int l7   = lane & 7;

    // per-lane staging source bases (h=0, r=0); chunk pre-swizzled by l8.
    // POOL8: B-row permutation perm(rho)=256by+128H+64dy+8w+4R+2e+dx with
    // dx=l8&1, dy=(l8>>1)&1, e=l8>>2 (bijective on the 256-row tile).
    const u16* pAs = Ab + (size_t)(m0 + w * 16 + l8) * K + (l7 ^ l8) * 8;
    const u16* pBs = POOL8
        ? Bb + (size_t)(n0 + 8 * w + 64 * ((l8 >> 1) & 1) + 2 * (l8 >> 2) + (l8 & 1)) * K + (l7 ^ l8) * 8
        : Bb + (size_t)(n0 + w * 16 + l8) * K + (l7 ^ l8) * 8;

    facc acc[8][4];
    #pragma unroll
    for (int i = 0; i < 8; ++i)
        #pragma unroll
        for (int j = 0; j < 4; ++j)
            acc[i][j] = (facc)0.0f;

    bfrag a[4][2];    // current M-half A frags
    bfrag bb[4][2];   // all 4 N frags (both halves live)

    const int nIter = K >> 7;   // K/128; K multiple of 128, nIter >= 2

    // prologue: tile0 full -> buf0; tile1 {B.h0,B.h1,A.h0} -> buf1
    STB8(0, 0, 0, 0); STB8(0, 0, 0, 1); STB8(0, 0, 1, 0); STB8(0, 0, 1, 1);
    STA8(0, 0, 0, 0); STA8(0, 0, 0, 1); STA8(0, 0, 1, 0); STA8(0, 0, 1, 1);
    STB8(1, 1, 0, 0); STB8(1, 1, 0, 1); STB8(1, 1, 1, 0); STB8(1, 1, 1, 1);
    STA8(1, 1, 0, 0); STA8(1, 1, 0, 1);
    VM6();            // tile0's 8 loads landed; tile1's 6 may fly
    BAR8();

    for (int i = 0; i < nIter; ++i) {
        const bool more = (i + 1 < nIter);
        const int t1 = 2 * i + 1, t2 = 2 * i + 2, t3 = 2 * i + 3;

        // ph1: quad(0,0) of tile 2i (buf0); stage t1.A.h1 -> buf1
        LDA8(0, 0); LDB8(0, 0);
        STA8(t1, 1, 1, 0); STA8(t1, 1, 1, 1);
        BAR8();
        __builtin_amdgcn_s_setprio(1); MM8(0, 0); __builtin_amdgcn_s_setprio(0);
        BAR8();
        // ph2: quad(0,1)
        LDB8(0, 1);
        BAR8();
        __builtin_amdgcn_s_setprio(1); MM8(0, 1); __builtin_amdgcn_s_setprio(0);
        BAR8();
        // ph3: quad(1,0); stage t2.B h0+h1 -> buf0 (B reads of buf0 ended ph2)
        LDA8(0, 1);
        if (more) { STB8(t2, 0, 0, 0); STB8(t2, 0, 0, 1); STB8(t2, 0, 1, 0); STB8(t2, 0, 1, 1); }
        BAR8();
        __builtin_amdgcn_s_setprio(1); MM8(1, 0); __builtin_amdgcn_s_setprio(0);
        BAR8();
        // ph4: quad(1,1); stage t2.A.h0 -> buf0 (A reads ended ph3); gate tile t1
        if (more) { STA8(t2, 0, 0, 0); STA8(t2, 0, 0, 1); VM6(); } else { VM0(); }
        BAR8();
        __builtin_amdgcn_s_setprio(1); MM8(1, 1); __builtin_amdgcn_s_setprio(0);
        BAR8();
        // ph5: quad(0,0) of tile 2i+1 (buf1); stage t2.A.h1 -> buf0
        LDA8(1, 0); LDB8(1, 0);
        if (more) { STA8(t2, 0, 1, 0); STA8(t2, 0, 1, 1); }
        BAR8();
        __builtin_amdgcn_s_setprio(1); MM8(0, 0); __builtin_amdgcn_s_setprio(0);
        BAR8();
        // ph6: quad(0,1)
        LDB8(1, 1);
        BAR8();
        __builtin_amdgcn_s_setprio(1); MM8(0, 1); __builtin_amdgcn_s_setprio(0);
        BAR8();
        // ph7: quad(1,0); stage t3.B h0+h1 -> buf1 (B reads of buf1 ended ph6)
        LDA8(1, 1);
        if (more) { STB8(t3, 1, 0, 0); STB8(t3, 1, 0, 1); STB8(t3, 1, 1, 0); STB8(t3, 1, 1, 1); }
        BAR8();
        __builtin_amdgcn_s_setprio(1); MM8(1, 0); __builtin_amdgcn_s_setprio(0);
        BAR8();
        // ph8: quad(1,1); stage t3.A.h0 -> buf1 (A reads ended ph7); gate tile t2
        if (more) { STA8(t3, 1, 0, 0); STA8(t3, 1, 0, 1); VM6(); } else { VM0(); }
        BAR8();
        __builtin_amdgcn_s_setprio(1); MM8(1, 1); __builtin_amdgcn_s_setprio(0);
        BAR8();
        // (next iter's ph1 stages t3.A.h1, completing tile t3)
    }

    if (POOL8) {
        // In-register 2x2 maxpool, then LDS-transposed dual dumps for fully
        // coalesced global stores. dumpP1 [64 sp][264 u16] feeds FAT rows;
        // dumpP2 [256 ch][72 u16] feeds FA rows. K-loop LDS is dead past the
        // final BAR8 (VM0 drained; frags in regs).
        u16* dumpP1 = (u16*)smem8;              // 64*264*2  = 33792 B
        u16* dumpP2 = (u16*)(smem8 + 36864);    // 256*72*2  = 36864 B
        const int a4  = ln >> 2;
        const int yp  = wc >> 1;
        const int xpb = (wc & 1) * 16 + a4;
        #pragma unroll
        for (int mi = 0; mi < 8; ++mi) {
            const int chl = wr * 128 + mi * 16 + q * 4;   // block-local channel base
            float bs0 = bias[m0 + chl + 0];
            float bs1 = bias[m0 + chl + 1];
            float bs2 = bias[m0 + chl + 2];
            float bs3 = bias[m0 + chl + 3];
            #pragma unroll
            for (int nf = 0; nf < 4; ++nf) {
                const int spl = yp * 32 + xpb + nf * 4;   // block-local pooled sp
                float p0 = acc[mi][nf][0] + bs0;
                float p1 = acc[mi][nf][1] + bs1;
                float p2 = acc[mi][nf][2] + bs2;
                float p3 = acc[mi][nf][3] + bs3;
                p0 = fmaxf(p0, __shfl_xor(p0, 1, 64)); p0 = fmaxf(p0, __shfl_xor(p0, 2, 64));
                p1 = fmaxf(p1, __shfl_xor(p1, 1, 64)); p1 = fmaxf(p1, __shfl_xor(p1, 2, 64));
                p2 = fmaxf(p2, __shfl_xor(p2, 1, 64)); p2 = fmaxf(p2, __shfl_xor(p2, 2, 64));
                p3 = fmaxf(p3, __shfl_xor(p3, 1, 64)); p3 = fmaxf(p3, __shfl_xor(p3, 2, 64));
                // FA-side per-lane scalar: ch = chl + (ln&3)
                float s01 = (ln & 1) ? p1 : p0;
                float s23 = (ln & 1) ? p3 : p2;
                float sel = (ln & 2) ? s23 : s01;
                dumpP2[(chl + (ln & 3)) * 72 + spl] = f2bf(sel);
                // FAT-side packed quad: one lane per window
                if ((ln & 3) == 0) {
                    uint2 pk;
                    pk.x = (unsigned)f2bf(p0) | ((unsigned)f2bf(p1) << 16);
                    pk.y = (unsigned)f2bf(p2) | ((unsigned)f2bf(p3) << 16);
                    *reinterpret_cast<uint2*>(&dumpP1[spl * 264 + chl]) = pk;
                }
            }
        }
        BAR8();
        u16* Cp  = C  + (size_t)b * strideC;    // FA  [ch][1024]
        u16* CTb = CT + (size_t)b * strideC;    // FAT [sp][1024]
        // FA pass: 256 ch x 64 sp, uint4 rows from dumpP2 (coalesced 128B/8 lanes)
        #pragma unroll
        for (int it = 0; it < 4; ++it) {
            int ch  = it * 64 + (t >> 3);
            int spg = t & 7;
            uint4 v = *reinterpret_cast<const uint4*>(&dumpP2[ch * 72 + spg * 8]);
            *reinterpret_cast<uint4*>(&Cp[(size_t)(m0 + ch) * 1024 + by * 64 + spg * 8]) = v;
        }
        // FAT pass: 64 sp rows x 32 uint4/row from dumpP1 (512B contiguous/row)
        #pragma unroll
        for (int it = 0; it < 4; ++it) {
            int linear = it * 512 + t;
            int spl = linear >> 5, cq = linear & 31;
            uint4 v = *reinterpret_cast<const uint4*>(&dumpP1[spl * 264 + cq * 8]);
            *reinterpret_cast<uint4*>(&CTb[(size_t)(by * 64 + spl) * 1024 + m0 + cq * 8]) = v;
        }
    } else {
        // plain bf16: dump 256x256 to LDS, re-read as uint4, 512B stores
        u16* dump = (u16*)smem8;
        #pragma unroll
        for (int mf = 0; mf < 8; ++mf)
            #pragma unroll
            for (int nf = 0; nf < 4; ++nf)
                #pragma unroll
                for (int r = 0; r < 4; ++r)
                    dump[(wr * 128 + mf * 16 + q * 4 + r) * 256 + wc * 64 + nf * 16 + ln] =
                        f2bf(acc[mf][nf][r]);
        BAR8();
        u16* Cb = C + (size_t)b * strideC;
        #pragma unroll
        for (int it = 0; it < 16; ++it) {
            int linear = t + it * 512;
            int row = linear >> 5, c16 = linear & 31;
            uint4 v = *reinterpret_cast<const uint4*>(dump + row * 256 + c16 * 8);
            *reinterpret_cast<uint4*>(Cb + (size_t)(m0 + row) * N + n0 + c16 * 8) = v;
        }
    }
}

// ---------------------------------------------------------------------------
// Row inverse-L2-norm of relu(fm): rinv[row] = 1/sqrt(sum relu(v)^2 + eps)
// ---------------------------------------------------------------------------
__global__ void norm_rk(const u16* __restrict__ fm, float* __restrict__ rinv) {
    __shared__ float red[4];
    const long row = blockIdx.x;
    const u16* p = fm + row * 1024;
    const int t = threadIdx.x;
    uint2 raw = *reinterpret_cast<const uint2*>(p + t * 4);
    float v0 = fmaxf(bf2f((u16)(raw.x & 0xFFFF)), 0.f);
    float v1 = fmaxf(bf2f((u16)(raw.x >> 16)), 0.f);
    float v2 = fmaxf(bf2f((u16)(raw.y & 0xFFFF)), 0.f);
    float v3 = fmaxf(bf2f((u16)(raw.y >> 16)), 0.f);
    float s = v0 * v0 + v1 * v1 + v2 * v2 + v3 * v3;
    for (int off = 32; off; off >>= 1) s += __shfl_down(s, off, 64);
    if ((t & 63) == 0) red[t >> 6] = s;
    __syncthreads();
    if (t == 0)
        rinv[row] = 1.0f / sqrtf(red[0] + red[1] + red[2] + red[3] + 1e-6f);
}

// ---------------------------------------------------------------------------
// Fused relu+scale+transpose: dst[q][p] = relu(src[p][q]) * rinv[p], per batch.
// ---------------------------------------------------------------------------
__global__ void transpose_scale_k(const u16* __restrict__ src,
                                  const float* __restrict__ rinv,
                                  u16* __restrict__ dst) {
    __shared__ u16 tile[64][65];
    const long S = 1048576;
    const int b  = blockIdx.z;
    const int c0 = blockIdx.x * 64;   // q
    const int r0 = blockIdx.y * 64;   // p
    const int x  = threadIdx.x;
    const int y0 = threadIdx.y;
    const u16* s = src + (size_t)b * S;
    const float* rv = rinv + (size_t)b * 1024;
    for (int i = 0; i < 8; ++i) {
        int r = y0 + i * 8;
        float v = fmaxf(bf2f(s[(size_t)(r0 + r) * 1024 + c0 + x]), 0.f) * rv[r0 + r];
        tile[r][x] = f2bf(v);
    }
    __syncthreads();
    u16* d = dst + (size_t)b * S;
    for (int i = 0; i < 8; ++i) {
        int c = y0 + i * 8;
        d[(size_t)(c0 + c) * 1024 + r0 + x] = tile[x][c];
    }
}

// ---------------------------------------------------------------------------
// Bilinear x2 upsample (align_corners): V fp32 (4096 ch-imgs, 32,32) -> out fp32
// ---------------------------------------------------------------------------
__global__ void upsample_k(const float* __restrict__ V, float* __restrict__ out, int total) {
    int idx = blockIdx.x * blockDim.x + threadIdx.x;
    if (idx >= total) return;
    int X  = idx & 63;
    int Y  = (idx >> 6) & 63;
    long bo = idx >> 12;
    const float* p = V + bo * 1024;
    const float sc = 31.0f / 63.0f;
    float ys = Y * sc;
    float xs = X * sc;
    int y0 = (int)ys; int x0 = (int)xs;
    int y1 = y0 + 1; if (y1 > 31) y1 = 31;
    int x1 = x0 + 1; if (x1 > 31) x1 = 31;
    float ty = ys - y0, tx = xs - x0;
    float v00 = p[y0 * 32 + x0], v01 = p[y0 * 32 + x1];
    float v10 = p[y1 * 32 + x0], v11 = p[y1 * 32 + x1];
    out[idx] = (1.f - ty) * ((1.f - tx) * v00 + tx * v01) + ty * ((1.f - tx) * v10 + tx * v11);
}

// ---------------------------------------------------------------------------
extern "C" void kernel_launch(void* const* d_in, const int* in_sizes, int n_in,
                              void* d_out, int out_size, void* d_ws, size_t ws_size,
                              hipStream_t stream) {
    const float* xa      = (const float*)d_in[0];   // (8,256,64,64)
    const float* xb      = (const float*)d_in[1];
    const float* conv_w  = (const float*)d_in[2];   // (1024,256)
    const float* conv_b  = (const float*)d_in[3];   // (1024,)
    const float* We      = (const float*)d_in[4];   // (1024,1024)
    const float* We2     = (const float*)d_in[5];   // (1024,1024)
    const float* conv2_w = (const float*)d_in[6];   // (256,1024)
    const float* conv2_b = (const float*)d_in[7];   // (256,)
    float* out = (float*)d_out;
    char* ws = (char*)d_ws;

    const long S1M = 1048576;
    const long MiB = 1048576;

    u16*   XT  = (u16*)(ws + 0);
    u16*   T1  = (u16*)(ws + 0);
    u16*   MT  = (u16*)(ws + 0);
    u16*   FA  = (u16*)(ws + 32 * MiB);
    u16*   FB  = (u16*)(ws + 48 * MiB);
    u16*   FAT = (u16*)(ws + 64 * MiB);
    u16*   FBT = (u16*)(ws + 80 * MiB);
    float* V   = (float*)(ws + 64 * MiB);
    u16*   FM  = (u16*)(ws + 96 * MiB);
    u16*   Z   = (u16*)(ws + 96 * MiB);
    u16*   CW  = (u16*)(ws + 128 * MiB);
    u16*   WE  = (u16*)(ws + 128 * MiB + 524288);
    u16*   WE2 = (u16*)(ws + 128 * MiB + 2621440);
    u16*   C2W = (u16*)(ws + 128 * MiB + 4718592);
    float* RIV = (float*)(ws + 128 * MiB + 5242880);   // 16x1024 fp32

    const dim3 tb64(64, 8);

    // 1. weights fp32 -> bf16
    cvt4_k<<<10240, 256, 0, stream>>>(conv_w, CW, We, WE, We2, WE2, conv2_w, C2W);

    // 2. input transpose+convert: XT[z][spatial][ch]
    transpose_in_k<<<dim3(64, 4, 16), tb64, 0, stream>>>(xa, xb, XT);

    // 3. conv1 + bias + 2x2 maxpool -> FA/FB (ch-major) + FAT/FBT (spatial-major)
    //    8-phase 256^2, M=1024 K=256, pool-permuted B staging, coalesced dumps
    gemm8_nt<false, 2><<<dim3(4, 16, 16), 512, 0, stream>>>(
        CW, CW, 0, XT, XT, S1M, FA, S1M, FAT, conv_b, 4096, 256);

    // 4. T1: path a = FBT . We^T ; path b = FAT . We2^T   (8-phase 256^2)
    gemm8_nt<true, 0><<<dim3(4, 4, 16), 512, 0, stream>>>(
        FBT, FAT, S1M, WE, WE2, 0, T1, S1M, nullptr, nullptr, 1024, 1024);

    // 5. fm: path a = T1 . FAT^T ; path b = T1 . FBT^T
    gemm8_nt<true, 0><<<dim3(4, 4, 16), 512, 0, stream>>>(
        T1, T1 + 8 * S1M, S1M, FAT, FBT, S1M, FM, S1M, nullptr, nullptr, 1024, 1024);

    // 6. row inverse norms of relu(fm)
    norm_rk<<<16384, 256, 0, stream>>>(FM, RIV);

    // 7. MT[q][p] = relu(fm[p][q]) * rinv[p]
    transpose_scale_k<<<dim3(16, 16, 16), tb64, 0, stream>>>(FM, RIV, MT);

    // 8. en: path a = FA . MT^T ; path b = FB . MT^T  -> Z (ch x spatial)
    gemm8_nt<true, 0><<<dim3(4, 4, 16), 512, 0, stream>>>(
        FA, FB, S1M, MT, MT + 8 * S1M, S1M, Z, S1M, nullptr, nullptr, 1024, 1024);

    // 9. conv2 + bias (fp32 out)
    gemm_nt<float, 1, false><<<dim3(2, 8, 16), 256, 0, stream>>>(
        C2W, C2W, 0, Z, Z, S1M, V, 256L * 1024, nullptr, conv2_b, 256, 1024, 1024);

    // 10. bilinear x2 upsample -> d_out
    upsample_k<<<65536, 256, 0, stream>>>(V, out, 16 * 256 * 4096);
}

// Round 8
// 369.754 us; speedup vs baseline: 1.0432x; 1.0432x over previous
//
#include <hip/hip_runtime.h>

typedef unsigned short u16;
typedef short bfrag __attribute__((ext_vector_type(8)));   // 8 bf16 (4 VGPRs) for MFMA A/B
typedef float facc  __attribute__((ext_vector_type(4)));   // 4 fp32 accumulator

__device__ __forceinline__ float bf2f(u16 u) {
    union { unsigned int i; float f; } v; v.i = ((unsigned int)u) << 16; return v.f;
}
__device__ __forceinline__ u16 f2bf(float f) {
    union { float f; unsigned int i; } v; v.f = f;
    unsigned int r = v.i + 0x7FFFu + ((v.i >> 16) & 1u);
    return (u16)(r >> 16);
}

__device__ __forceinline__ void store_out(u16* p, float v)   { *p = f2bf(v); }
__device__ __forceinline__ void store_out(float* p, float v) { *p = v; }

// async global->LDS, 16B per lane; LDS dest = wave-uniform base + lane*16
__device__ __forceinline__ void gl2lds16(const u16* g, char* l) {
    __builtin_amdgcn_global_load_lds(
        (const __attribute__((address_space(1))) unsigned int*)g,
        (__attribute__((address_space(3))) unsigned int*)l,
        16, 0, 0);
}

// ---------------------------------------------------------------------------
// fp32 -> bf16 convert for the 4 weight tensors in one launch
// ---------------------------------------------------------------------------
__global__ void cvt4_k(const float* __restrict__ s0, u16* __restrict__ d0,
                       const float* __restrict__ s1, u16* __restrict__ d1,
                       const float* __restrict__ s2, u16* __restrict__ d2,
                       const float* __restrict__ s3, u16* __restrict__ d3) {
    int i = blockIdx.x * blockDim.x + threadIdx.x;
    if (i < 262144)        d0[i] = f2bf(s0[i]);
    else if (i < 1310720)  d1[i - 262144] = f2bf(s1[i - 262144]);
    else if (i < 2359296)  d2[i - 1310720] = f2bf(s2[i - 1310720]);
    else                   d3[i - 2359296] = f2bf(s3[i - 2359296]);
}

// ---------------------------------------------------------------------------
// Input transpose + fp32->bf16: xa/xb (b,256,4096) -> XT (16b, 4096, 256)
// ---------------------------------------------------------------------------
__global__ void transpose_in_k(const float* __restrict__ srcA,
                               const float* __restrict__ srcB,
                               u16* __restrict__ dst) {
    __shared__ u16 tile[64][65];
    const long SX = 1048576;  // 256*4096
    const int z  = blockIdx.z;
    const int c0 = blockIdx.x * 64;   // spatial
    const int r0 = blockIdx.y * 64;   // channel
    const int x  = threadIdx.x;
    const int y0 = threadIdx.y;
    const float* s = (z < 8 ? srcA : srcB) + (size_t)(z & 7) * SX;
    for (int i = 0; i < 8; ++i) {
        int r = y0 + i * 8;
        tile[r][x] = f2bf(s[(size_t)(r0 + r) * 4096 + c0 + x]);
    }
    __syncthreads();
    u16* d = dst + (size_t)z * SX;
    for (int i = 0; i < 8; ++i) {
        int c = y0 + i * 8;
        d[(size_t)(c0 + c) * 256 + r0 + x] = tile[x][c];
    }
}

// ---------------------------------------------------------------------------
// 128x128 NT GEMM (m97-class structure), kept for MODE 1 (conv2, small grid).
// ---------------------------------------------------------------------------
template <typename OutT, int MODE, bool PAIRED>
__global__ __launch_bounds__(256)
void gemm_nt(const u16* __restrict__ A0, const u16* __restrict__ A1, long strideA,
             const u16* __restrict__ B0, const u16* __restrict__ B1, long strideBT,
             OutT* __restrict__ C, long strideC, u16* __restrict__ CT,
             const float* __restrict__ bias, int M, int N, int K) {
    __shared__ __align__(16) char smem[32768];
    char* As = smem;
    char* Bs = smem + 16384;

    const int gx = gridDim.x, gy = gridDim.y;
    long id = blockIdx.x + (long)gx * (blockIdx.y + (long)gy * blockIdx.z);
    long total = (long)gx * gy * gridDim.z;
    long nid = (id & 7) * (total >> 3) + (id >> 3);
    const int bx = (int)(nid % gx);
    long rr = nid / gx;
    const int by = (int)(rr % gy);
    const int b  = (int)(rr / gy);

    const int m0 = bx * 128;
    const int n0 = by * 128;

    const u16* Ab; const u16* Bb;
    if (PAIRED) {
        const int bl = b & 7;
        Ab = (b < 8 ? A0 : A1) + (size_t)bl * strideA;
        Bb = (b < 8 ? B0 : B1) + (size_t)bl * strideBT;
    } else {
        Ab = A0 + (size_t)b * strideA;
        Bb = B0 + (size_t)b * strideBT;
    }

    const int t    = threadIdx.x;
    const int lane = t & 63;
    const int w    = t >> 6;
    const int wm   = (w & 1) * 64;
    const int wn   = (w >> 1) * 64;
    const int q    = lane >> 4;
    const int ln   = lane & 15;

    const int s0 = w * 64 + lane;
    const int s1 = s0 + 256;
    const int r0s = s0 >> 2, c0s = (s0 & 3) * 8;
    const int r1s = s1 >> 2, c1s = (s1 & 3) * 8;

    const u16* pA0 = Ab + (size_t)(m0 + r0s) * K + c0s;
    const u16* pA1 = Ab + (size_t)(m0 + r1s) * K + c1s;
    const u16* pB0 = Bb + (size_t)(n0 + r0s) * K + c0s;
    const u16* pB1 = Bb + (size_t)(n0 + r1s) * K + c1s;

    facc acc[4][4];
    for (int i = 0; i < 4; ++i)
        for (int j = 0; j < 4; ++j)
            acc[i][j] = (facc)0.0f;

    const int nK = K >> 6;
    for (int kt = 0; kt < nK; ++kt) {
        const int k0 = kt << 6;
        gl2lds16(pA0 + k0,      As + s0 * 16);
        gl2lds16(pA1 + k0,      As + s1 * 16);
        gl2lds16(pA0 + k0 + 32, As + 8192 + s0 * 16);
        gl2lds16(pA1 + k0 + 32, As + 8192 + s1 * 16);
        gl2lds16(pB0 + k0,      Bs + s0 * 16);
        gl2lds16(pB1 + k0,      Bs + s1 * 16);
        gl2lds16(pB0 + k0 + 32, Bs + 8192 + s0 * 16);
        gl2lds16(pB1 + k0 + 32, Bs + 8192 + s1 * 16);
        __syncthreads();
        for (int j = 0; j < 2; ++j) {
            const char* Aj = As + j * 8192;
            const char* Bj = Bs + j * 8192;
            bfrag af[4], bfr[4];
            for (int mt = 0; mt < 4; ++mt)
                af[mt] = *reinterpret_cast<const bfrag*>(Aj + (wm + mt * 16 + ln) * 64 + q * 16);
            for (int nt = 0; nt < 4; ++nt)
                bfr[nt] = *reinterpret_cast<const bfrag*>(Bj + (wn + nt * 16 + ln) * 64 + q * 16);
            for (int mt = 0; mt < 4; ++mt)
                for (int nt = 0; nt < 4; ++nt)
                    acc[mt][nt] = __builtin_amdgcn_mfma_f32_16x16x32_bf16(af[mt], bfr[nt], acc[mt][nt], 0, 0, 0);
        }
        __syncthreads();
    }

    if (MODE == 0) {
        u16* Cb = (u16*)C + (size_t)b * strideC;
        u16* dump = (u16*)smem;
        for (int mt = 0; mt < 4; ++mt)
            for (int nt = 0; nt < 4; ++nt)
                for (int r = 0; r < 4; ++r)
                    dump[(wm + mt * 16 + q * 4 + r) * 128 + wn + nt * 16 + ln] = f2bf(acc[mt][nt][r]);
        __syncthreads();
        for (int i = 0; i < 8; ++i) {
            const int row = w * 32 + i * 4 + (lane >> 4);
            const uint4 v = *reinterpret_cast<const uint4*>(dump + row * 128 + (lane & 15) * 8);
            *reinterpret_cast<uint4*>(Cb + (size_t)(m0 + row) * N + n0 + (lane & 15) * 8) = v;
        }
    } else {
        OutT* Cb = C + (size_t)b * strideC;
        for (int mt = 0; mt < 4; ++mt) {
            const int rbase = m0 + wm + mt * 16 + q * 4;
            for (int nt = 0; nt < 4; ++nt) {
                const int col = n0 + wn + nt * 16 + ln;
                for (int r = 0; r < 4; ++r)
                    store_out(&Cb[(size_t)(rbase + r) * N + col], acc[mt][nt][r] + bias[rbase + r]);
            }
        }
    }
}

// ---------------------------------------------------------------------------
// Pool conv1 GEMM, latency-optimized: 128x128 tile, BK=32, double-buffered
// 2-phase counted-vmcnt loop in 32 KiB LDS (4 blocks/CU co-residency).
//   LDS: buf k&1 at (k&1)*16384: A [0,8K), B [8K,16K); 128 rows x 64B.
//   Chunk-XOR swizzle: physical 16B-chunk p of row r holds logical chunk
//   p ^ ((r>>1)&3) — applied via pre-swizzled global source (gl2lds dest
//   linear) + same XOR on ds_read addresses. Fragment reads then spread
//   16 lanes over 4 chunk-slots x 2 bank-bases = 2-way (free).
//   B rows pool-permuted (round-1 verified): LDS row rho <- spatial
//   (2*by + ((rho>>1)&1))*64 + (rho>>2)*2 + (rho&1), so each 2x2 pool
//   window sits in lanes 4a..4a+3 -> in-register shfl_xor butterfly.
//   Loop: {stage t+1 -> buf[(t+1)&1]; vmcnt(4); s_barrier; ds_read+MFMA
//   buf[t&1]; s_barrier} — vmcnt never drains to 0 mid-loop.
// ---------------------------------------------------------------------------
#define BARP() do { asm volatile("" ::: "memory"); __builtin_amdgcn_s_barrier(); asm volatile("" ::: "memory"); } while (0)
#define VM4P() asm volatile("s_waitcnt vmcnt(4)" ::: "memory")
#define VM0P() asm volatile("s_waitcnt vmcnt(0)" ::: "memory")

#define STGP(KT, BUF) do { \
    gl2lds16(pA0 + (KT) * 32, smem + (BUF) * 16384 + s0 * 16); \
    gl2lds16(pA1 + (KT) * 32, smem + (BUF) * 16384 + s1 * 16); \
    gl2lds16(pB0 + (KT) * 32, smem + (BUF) * 16384 + 8192 + s0 * 16); \
    gl2lds16(pB1 + (KT) * 32, smem + (BUF) * 16384 + 8192 + s1 * 16); \
} while (0)

__global__ __launch_bounds__(256)
void gemm2p_pool(const u16* __restrict__ A, const u16* __restrict__ B0, long strideBT,
                 u16* __restrict__ C, long strideC, u16* __restrict__ CT,
                 const float* __restrict__ bias, int K) {
    __shared__ __align__(16) char smem[32768];

    const int gx = gridDim.x, gy = gridDim.y;
    long id = blockIdx.x + (long)gx * (blockIdx.y + (long)gy * blockIdx.z);
    long total = (long)gx * gy * gridDim.z;
    long nid = (id & 7) * (total >> 3) + (id >> 3);
    const int bx = (int)(nid % gx);
    long rr = nid / gx;
    const int by = (int)(rr % gy);
    const int b  = (int)(rr / gy);
    const int m0 = bx * 128;

    const u16* Bb = B0 + (size_t)b * strideBT;

    const int t    = threadIdx.x;
    const int lane = t & 63;
    const int w    = t >> 6;
    const int wm   = (w & 1) * 64;
    const int wn   = (w >> 1) * 64;
    const int q    = lane >> 4;
    const int ln   = lane & 15;

    // staging slots: slot s -> row s>>2, chunk s&3 (16B each)
    const int s0 = w * 64 + lane;          // [0,256)
    const int s1 = s0 + 256;               // [256,512)
    const int r0s = s0 >> 2, c0s = s0 & 3;
    const int r1s = s1 >> 2, c1s = s1 & 3;
    const int x0 = (r0s >> 1) & 3, x1 = (r1s >> 1) & 3;   // chunk-XOR keys
    // pool-permuted B rows (round-1 verified mapping)
    const int gr0 = (2 * by + ((r0s >> 1) & 1)) * 64 + (r0s >> 2) * 2 + (r0s & 1);
    const int gr1 = (2 * by + ((r1s >> 1) & 1)) * 64 + (r1s >> 2) * 2 + (r1s & 1);

    const u16* pA0 = A  + (size_t)(m0 + r0s) * K + (c0s ^ x0) * 8;
    const u16* pA1 = A  + (size_t)(m0 + r1s) * K + (c1s ^ x1) * 8;
    const u16* pB0 = Bb + (size_t)gr0 * K + (c0s ^ x0) * 8;
    const u16* pB1 = Bb + (size_t)gr1 * K + (c1s ^ x1) * 8;

    facc acc[4][4];
    #pragma unroll
    for (int i = 0; i < 4; ++i)
        #pragma unroll
        for (int j = 0; j < 4; ++j)
            acc[i][j] = (facc)0.0f;

    const int nK = K >> 5;     // BK=32 iterations (K=256 -> 8)

    STGP(0, 0);                // prologue: tile 0 -> buf 0
    for (int kt = 0; kt < nK; ++kt) {
        const bool more = (kt + 1 < nK);
        if (more) { STGP(kt + 1, (kt + 1) & 1); VM4P(); } else { VM0P(); }
        BARP();
        const char* Aj = smem + (kt & 1) * 16384;
        const char* Bj = Aj + 8192;
        bfrag af[4], bfr[4];
        #pragma unroll
        for (int mt = 0; mt < 4; ++mt) {
            const int row = wm + mt * 16 + ln;
            af[mt] = *reinterpret_cast<const bfrag*>(Aj + row * 64 + ((q ^ ((row >> 1) & 3)) << 4));
        }
        #pragma unroll
        for (int nt = 0; nt < 4; ++nt) {
            const int row = wn + nt * 16 + ln;
            bfr[nt] = *reinterpret_cast<const bfrag*>(Bj + row * 64 + ((q ^ ((row >> 1) & 3)) << 4));
        }
        #pragma unroll
        for (int mt = 0; mt < 4; ++mt)
            #pragma unroll
            for (int nt = 0; nt < 4; ++nt)
                acc[mt][nt] = __builtin_amdgcn_mfma_f32_16x16x32_bf16(af[mt], bfr[nt], acc[mt][nt], 0, 0, 0);
        BARP();
    }

    // in-register 2x2 maxpool epilogue (round-1 verified)
    u16* Cp  = C  + (size_t)b * strideC;    // FA  [ch][1024]
    u16* CTb = CT + (size_t)b * strideC;    // FAT [sp][1024]
    const int a = ln >> 2;
    #pragma unroll
    for (int mt = 0; mt < 4; ++mt) {
        const int chb = wm + mt * 16 + q * 4;
        float bs0 = bias[m0 + chb + 0];
        float bs1 = bias[m0 + chb + 1];
        float bs2 = bias[m0 + chb + 2];
        float bs3 = bias[m0 + chb + 3];
        #pragma unroll
        for (int nt = 0; nt < 4; ++nt) {
            const int xp = (wn >> 2) + nt * 4 + a;
            float p0 = acc[mt][nt][0] + bs0;
            float p1 = acc[mt][nt][1] + bs1;
            float p2 = acc[mt][nt][2] + bs2;
            float p3 = acc[mt][nt][3] + bs3;
            p0 = fmaxf(p0, __shfl_xor(p0, 1, 64)); p0 = fmaxf(p0, __shfl_xor(p0, 2, 64));
            p1 = fmaxf(p1, __shfl_xor(p1, 1, 64)); p1 = fmaxf(p1, __shfl_xor(p1, 2, 64));
            p2 = fmaxf(p2, __shfl_xor(p2, 1, 64)); p2 = fmaxf(p2, __shfl_xor(p2, 2, 64));
            p3 = fmaxf(p3, __shfl_xor(p3, 1, 64)); p3 = fmaxf(p3, __shfl_xor(p3, 2, 64));
            float s01 = (ln & 1) ? p1 : p0;
            float s23 = (ln & 1) ? p3 : p2;
            float sel = (ln & 2) ? s23 : s01;
            Cp[(size_t)(m0 + chb + (ln & 3)) * 1024 + by * 32 + xp] = f2bf(sel);
            if ((ln & 3) == 0) {
                uint2 pk;
                pk.x = (unsigned)f2bf(p0) | ((unsigned)f2bf(p1) << 16);
                pk.y = (unsigned)f2bf(p2) | ((unsigned)f2bf(p3) << 16);
                *reinterpret_cast<uint2*>(&CTb[(size_t)(by * 32 + xp) * 1024 + m0 + chb]) = pk;
            }
        }
    }
}

// ---------------------------------------------------------------------------
// 256x256 8-phase NT GEMM (T2+T3+T4+T5), bf16 in, K multiple of 128.
// Used for steps 4/5/8 (MODE8=0). See round-1/2 notes for schedule + ledger.
// ---------------------------------------------------------------------------
#define BAR8() do { asm volatile("" ::: "memory"); __builtin_amdgcn_s_barrier(); asm volatile("" ::: "memory"); } while (0)
#define VM6() asm volatile("s_waitcnt vmcnt(6)" ::: "memory")
#define VM0() asm volatile("s_waitcnt vmcnt(0)" ::: "memory")

#define LDA8(BUF, MH) \
    _Pragma("unroll") for (int mf = 0; mf < 4; ++mf) { \
        _Pragma("unroll") for (int ks = 0; ks < 2; ++ks) \
            a[mf][ks] = *reinterpret_cast<const bfrag*>(Ab8 + (BUF) * 32768 + \
                (wr * 128 + ((MH) * 4 + mf) * 16 + ln) * 128 + (((ks * 4 + q) ^ ln7) << 4)); }

#define LDB8(BUF, NH) \
    _Pragma("unroll") for (int nf = 0; nf < 2; ++nf) { \
        _Pragma("unroll") for (int ks = 0; ks < 2; ++ks) \
            bb[(NH) * 2 + nf][ks] = *reinterpret_cast<const bfrag*>(Bb8 + (BUF) * 32768 + \
                (wc * 64 + ((NH) * 2 + nf) * 16 + ln) * 128 + (((ks * 4 + q) ^ ln7) << 4)); }

#define MM8(MH, NH) \
    _Pragma("unroll") for (int mf = 0; mf < 4; ++mf) \
    _Pragma("unroll") for (int nf = 0; nf < 2; ++nf) \
    _Pragma("unroll") for (int ks = 0; ks < 2; ++ks) \
        acc[(MH) * 4 + mf][(NH) * 2 + nf] = __builtin_amdgcn_mfma_f32_16x16x32_bf16( \
            a[mf][ks], bb[(NH) * 2 + nf][ks], acc[(MH) * 4 + mf][(NH) * 2 + nf], 0, 0, 0);

#define STA8(KT, BUF, H, R) gl2lds16(pAs + (size_t)((H) * 128 + (R) * 8) * K + (KT) * 64, \
        Ab8 + (BUF) * 32768 + (H) * 16384 + (w * 2 + (R)) * 1024 + lane * 16)
#define STB8(KT, BUF, H, R) gl2lds16(pBs + (size_t)((H) * 128 + (R) * 8) * K + (KT) * 64, \
        Bb8 + (BUF) * 32768 + (H) * 16384 + (w * 2 + (R)) * 1024 + lane * 16)

template <bool PAIRED>
__global__ __launch_bounds__(512, 1)
void gemm8_nt(const u16* __restrict__ A0, const u16* __restrict__ A1, long strideA,
              const u16* __restrict__ B0, const u16* __restrict__ B1, long strideBT,
              u16* __restrict__ C, long strideC, int N, int K) {
    __shared__ __align__(16) char smem8[131072];
    char* Ab8 = smem8;
    char* Bb8 = smem8 + 65536;

    const int gx = gridDim.x, gy = gridDim.y;
    long id = blockIdx.x + (long)gx * (blockIdx.y + (long)gy * blockIdx.z);
    long total = (long)gx * gy * gridDim.z;
    long nid = (id & 7) * (total >> 3) + (id >> 3);
    const int bx = (int)(nid % gx);
    long rr = nid / gx;
    const int by = (int)(rr % gy);
    const int b  = (int)(rr / gy);
    const int m0 = bx * 256, n0 = by * 256;

    const u16* Ab; const u16* Bb;
    if (PAIRED) {
        const int bl = b & 7;
        Ab = (b < 8 ? A0 : A1) + (size_t)bl * strideA;
        Bb = (b < 8 ? B0 : B1) + (size_t)bl * strideBT;
    } else {
        Ab = A0 + (size_t)b * strideA;
        Bb = B0 + (size_t)b * strideBT;
    }

    const int t    = threadIdx.x;
    const int lane = t & 63;
    const int w    = t >> 6;          // 0..7
    const int wr   = w >> 2;          // 0..1  (M half)
    const int wc   = w & 3;           // 0..3  (N quarter)
    const int q    = lane >> 4;
    const int ln   = lane & 15;
    const int ln7  = ln & 7;
    const int l8   = lane >> 3;
    const int l7   = lane & 7;

    const u16* pAs = Ab + (size_t)(m0 + w * 16 + l8) * K + (l7 ^ l8) * 8;
    const u16* pBs = Bb + (size_t)(n0 + w * 16 + l8) * K + (l7 ^ l8) * 8;

    facc acc[8][4];
    #pragma unroll
    for (int i = 0; i < 8; ++i)
        #pragma unroll
        for (int j = 0; j < 4; ++j)
            acc[i][j] = (facc)0.0f;

    bfrag a[4][2];
    bfrag bb[4][2];

    const int nIter = K >> 7;

    STB8(0, 0, 0, 0); STB8(0, 0, 0, 1); STB8(0, 0, 1, 0); STB8(0, 0, 1, 1);
    STA8(0, 0, 0, 0); STA8(0, 0, 0, 1); STA8(0, 0, 1, 0); STA8(0, 0, 1, 1);
    STB8(1, 1, 0, 0); STB8(1, 1, 0, 1); STB8(1, 1, 1, 0); STB8(1, 1, 1, 1);
    STA8(1, 1, 0, 0); STA8(1, 1, 0, 1);
    VM6();
    BAR8();

    for (int i = 0; i < nIter; ++i) {
        const bool more = (i + 1 < nIter);
        const int t1 = 2 * i + 1, t2 = 2 * i + 2, t3 = 2 * i + 3;

        LDA8(0, 0); LDB8(0, 0);
        STA8(t1, 1, 1, 0); STA8(t1, 1, 1, 1);
        BAR8();
        __builtin_amdgcn_s_setprio(1); MM8(0, 0); __builtin_amdgcn_s_setprio(0);
        BAR8();
        LDB8(0, 1);
        BAR8();
        __builtin_amdgcn_s_setprio(1); MM8(0, 1); __builtin_amdgcn_s_setprio(0);
        BAR8();
        LDA8(0, 1);
        if (more) { STB8(t2, 0, 0, 0); STB8(t2, 0, 0, 1); STB8(t2, 0, 1, 0); STB8(t2, 0, 1, 1); }
        BAR8();
        __builtin_amdgcn_s_setprio(1); MM8(1, 0); __builtin_amdgcn_s_setprio(0);
        BAR8();
        if (more) { STA8(t2, 0, 0, 0); STA8(t2, 0, 0, 1); VM6(); } else { VM0(); }
        BAR8();
        __builtin_amdgcn_s_setprio(1); MM8(1, 1); __builtin_amdgcn_s_setprio(0);
        BAR8();
        LDA8(1, 0); LDB8(1, 0);
        if (more) { STA8(t2, 0, 1, 0); STA8(t2, 0, 1, 1); }
        BAR8();
        __builtin_amdgcn_s_setprio(1); MM8(0, 0); __builtin_amdgcn_s_setprio(0);
        BAR8();
        LDB8(1, 1);
        BAR8();
        __builtin_amdgcn_s_setprio(1); MM8(0, 1); __builtin_amdgcn_s_setprio(0);
        BAR8();
        LDA8(1, 1);
        if (more) { STB8(t3, 1, 0, 0); STB8(t3, 1, 0, 1); STB8(t3, 1, 1, 0); STB8(t3, 1, 1, 1); }
        BAR8();
        __builtin_amdgcn_s_setprio(1); MM8(1, 0); __builtin_amdgcn_s_setprio(0);
        BAR8();
        if (more) { STA8(t3, 1, 0, 0); STA8(t3, 1, 0, 1); VM6(); } else { VM0(); }
        BAR8();
        __builtin_amdgcn_s_setprio(1); MM8(1, 1); __builtin_amdgcn_s_setprio(0);
        BAR8();
    }

    // epilogue: dump 256x256 bf16 to LDS, re-read as uint4, 512B stores
    u16* dump = (u16*)smem8;
    #pragma unroll
    for (int mf = 0; mf < 8; ++mf)
        #pragma unroll
        for (int nf = 0; nf < 4; ++nf)
            #pragma unroll
            for (int r = 0; r < 4; ++r)
                dump[(wr * 128 + mf * 16 + q * 4 + r) * 256 + wc * 64 + nf * 16 + ln] =
                    f2bf(acc[mf][nf][r]);
    BAR8();
    u16* Cb = C + (size_t)b * strideC;
    #pragma unroll
    for (int it = 0; it < 16; ++it) {
        int linear = t + it * 512;
        int row = linear >> 5, c16 = linear & 31;
        uint4 v = *reinterpret_cast<const uint4*>(dump + row * 256 + c16 * 8);
        *reinterpret_cast<uint4*>(Cb + (size_t)(m0 + row) * N + n0 + c16 * 8) = v;
    }
}

// ---------------------------------------------------------------------------
// Row inverse-L2-norm of relu(fm): rinv[row] = 1/sqrt(sum relu(v)^2 + eps)
// ---------------------------------------------------------------------------
__global__ void norm_rk(const u16* __restrict__ fm, float* __restrict__ rinv) {
    __shared__ float red[4];
    const long row = blockIdx.x;
    const u16* p = fm + row * 1024;
    const int t = threadIdx.x;
    uint2 raw = *reinterpret_cast<const uint2*>(p + t * 4);
    float v0 = fmaxf(bf2f((u16)(raw.x & 0xFFFF)), 0.f);
    float v1 = fmaxf(bf2f((u16)(raw.x >> 16)), 0.f);
    float v2 = fmaxf(bf2f((u16)(raw.y & 0xFFFF)), 0.f);
    float v3 = fmaxf(bf2f((u16)(raw.y >> 16)), 0.f);
    float s = v0 * v0 + v1 * v1 + v2 * v2 + v3 * v3;
    for (int off = 32; off; off >>= 1) s += __shfl_down(s, off, 64);
    if ((t & 63) == 0) red[t >> 6] = s;
    __syncthreads();
    if (t == 0)
        rinv[row] = 1.0f / sqrtf(red[0] + red[1] + red[2] + red[3] + 1e-6f);
}

// ---------------------------------------------------------------------------
// Fused relu+scale+transpose: dst[q][p] = relu(src[p][q]) * rinv[p], per batch.
// ---------------------------------------------------------------------------
__global__ void transpose_scale_k(const u16* __restrict__ src,
                                  const float* __restrict__ rinv,
                                  u16* __restrict__ dst) {
    __shared__ u16 tile[64][65];
    const long S = 1048576;
    const int b  = blockIdx.z;
    const int c0 = blockIdx.x * 64;   // q
    const int r0 = blockIdx.y * 64;   // p
    const int x  = threadIdx.x;
    const int y0 = threadIdx.y;
    const u16* s = src + (size_t)b * S;
    const float* rv = rinv + (size_t)b * 1024;
    for (int i = 0; i < 8; ++i) {
        int r = y0 + i * 8;
        float v = fmaxf(bf2f(s[(size_t)(r0 + r) * 1024 + c0 + x]), 0.f) * rv[r0 + r];
        tile[r][x] = f2bf(v);
    }
    __syncthreads();
    u16* d = dst + (size_t)b * S;
    for (int i = 0; i < 8; ++i) {
        int c = y0 + i * 8;
        d[(size_t)(c0 + c) * 1024 + r0 + x] = tile[x][c];
    }
}

// ---------------------------------------------------------------------------
// Bilinear x2 upsample (align_corners): V fp32 (4096 ch-imgs, 32,32) -> out fp32
// ---------------------------------------------------------------------------
__global__ void upsample_k(const float* __restrict__ V, float* __restrict__ out, int total) {
    int idx = blockIdx.x * blockDim.x + threadIdx.x;
    if (idx >= total) return;
    int X  = idx & 63;
    int Y  = (idx >> 6) & 63;
    long bo = idx >> 12;
    const float* p = V + bo * 1024;
    const float sc = 31.0f / 63.0f;
    float ys = Y * sc;
    float xs = X * sc;
    int y0 = (int)ys; int x0 = (int)xs;
    int y1 = y0 + 1; if (y1 > 31) y1 = 31;
    int x1 = x0 + 1; if (x1 > 31) x1 = 31;
    float ty = ys - y0, tx = xs - x0;
    float v00 = p[y0 * 32 + x0], v01 = p[y0 * 32 + x1];
    float v10 = p[y1 * 32 + x0], v11 = p[y1 * 32 + x1];
    out[idx] = (1.f - ty) * ((1.f - tx) * v00 + tx * v01) + ty * ((1.f - tx) * v10 + tx * v11);
}

// ---------------------------------------------------------------------------
extern "C" void kernel_launch(void* const* d_in, const int* in_sizes, int n_in,
                              void* d_out, int out_size, void* d_ws, size_t ws_size,
                              hipStream_t stream) {
    const float* xa      = (const float*)d_in[0];   // (8,256,64,64)
    const float* xb      = (const float*)d_in[1];
    const float* conv_w  = (const float*)d_in[2];   // (1024,256)
    const float* conv_b  = (const float*)d_in[3];   // (1024,)
    const float* We      = (const float*)d_in[4];   // (1024,1024)
    const float* We2     = (const float*)d_in[5];   // (1024,1024)
    const float* conv2_w = (const float*)d_in[6];   // (256,1024)
    const float* conv2_b = (const float*)d_in[7];   // (256,)
    float* out = (float*)d_out;
    char* ws = (char*)d_ws;

    const long S1M = 1048576;
    const long MiB = 1048576;

    u16*   XT  = (u16*)(ws + 0);
    u16*   T1  = (u16*)(ws + 0);
    u16*   MT  = (u16*)(ws + 0);
    u16*   FA  = (u16*)(ws + 32 * MiB);
    u16*   FB  = (u16*)(ws + 48 * MiB);
    u16*   FAT = (u16*)(ws + 64 * MiB);
    u16*   FBT = (u16*)(ws + 80 * MiB);
    float* V   = (float*)(ws + 64 * MiB);
    u16*   FM  = (u16*)(ws + 96 * MiB);
    u16*   Z   = (u16*)(ws + 96 * MiB);
    u16*   CW  = (u16*)(ws + 128 * MiB);
    u16*   WE  = (u16*)(ws + 128 * MiB + 524288);
    u16*   WE2 = (u16*)(ws + 128 * MiB + 2621440);
    u16*   C2W = (u16*)(ws + 128 * MiB + 4718592);
    float* RIV = (float*)(ws + 128 * MiB + 5242880);   // 16x1024 fp32

    const dim3 tb64(64, 8);

    // 1. weights fp32 -> bf16
    cvt4_k<<<10240, 256, 0, stream>>>(conv_w, CW, We, WE, We2, WE2, conv2_w, C2W);

    // 2. input transpose+convert: XT[z][spatial][ch]
    transpose_in_k<<<dim3(64, 4, 16), tb64, 0, stream>>>(xa, xb, XT);

    // 3. conv1 + bias + 2x2 maxpool -> FA/FB (ch-major) + FAT/FBT (spatial-major)
    //    latency-optimized 128^2 BK=32 2-phase, 32 KiB LDS, high co-residency
    gemm2p_pool<<<dim3(8, 32, 16), 256, 0, stream>>>(
        CW, XT, S1M, FA, S1M, FAT, conv_b, 256);

    // 4. T1: path a = FBT . We^T ; path b = FAT . We2^T   (8-phase 256^2)
    gemm8_nt<true><<<dim3(4, 4, 16), 512, 0, stream>>>(
        FBT, FAT, S1M, WE, WE2, 0, T1, S1M, 1024, 1024);

    // 5. fm: path a = T1 . FAT^T ; path b = T1 . FBT^T
    gemm8_nt<true><<<dim3(4, 4, 16), 512, 0, stream>>>(
        T1, T1 + 8 * S1M, S1M, FAT, FBT, S1M, FM, S1M, 1024, 1024);

    // 6. row inverse norms of relu(fm)
    norm_rk<<<16384, 256, 0, stream>>>(FM, RIV);

    // 7. MT[q][p] = relu(fm[p][q]) * rinv[p]
    transpose_scale_k<<<dim3(16, 16, 16), tb64, 0, stream>>>(FM, RIV, MT);

    // 8. en: path a = FA . MT^T ; path b = FB . MT^T  -> Z (ch x spatial)
    gemm8_nt<true><<<dim3(4, 4, 16), 512, 0, stream>>>(
        FA, FB, S1M, MT, MT + 8 * S1M, S1M, Z, S1M, 1024, 1024);

    // 9. conv2 + bias (fp32 out)
    gemm_nt<float, 1, false><<<dim3(2, 8, 16), 256, 0, stream>>>(
        C2W, C2W, 0, Z, Z, S1M, V, 256L * 1024, nullptr, conv2_b, 256, 1024, 1024);

    // 10. bilinear x2 upsample -> d_out
    upsample_k<<<65536, 256, 0, stream>>>(V, out, 16 * 256 * 4096);
}